// Round 7
// baseline (635.196 us; speedup 1.0000x reference)
//
#include <hip/hip_runtime.h>
#include <hip/hip_bf16.h>
#include <hip/hip_fp16.h>

#define UNITS 512
#define D_DEC 1024
#define D_ENC 1024
#define BATCH 32
#define S_LEN 2048

typedef _Float16 f16x8 __attribute__((ext_vector_type(8)));
typedef float f32x4 __attribute__((ext_vector_type(4)));

__device__ inline float tanh_fast(float x) {
    float e = __expf(2.f * x);
    return 1.f - 2.f * __builtin_amdgcn_rcpf(e + 1.f);
}

// ---------------- prep: transpose + convert W2 [1024][512] f32 -> W2h [512][1024] f16
__global__ __launch_bounds__(256) void k_prep_w2(const float* __restrict__ W2,
                                                 _Float16* __restrict__ W2h) {
    __shared__ float tile[32][33];
    const int kb = blockIdx.x * 32;
    const int nb = blockIdx.y * 32;
    const int tx = threadIdx.x;
    const int ty = threadIdx.y;
    for (int i = 0; i < 32; i += 8)
        tile[ty + i][tx] = W2[(size_t)(kb + ty + i) * UNITS + nb + tx];
    __syncthreads();
    for (int i = 0; i < 32; i += 8)
        W2h[(size_t)(nb + ty + i) * D_DEC + kb + tx] = (_Float16)tile[tx][ty + i];
}

// ---------------- query
__global__ __launch_bounds__(1024) void k_query(const float* __restrict__ dec,
                                                const float* __restrict__ W1,
                                                const float* __restrict__ b1,
                                                float* __restrict__ query) {
    const int u = blockIdx.x * 32 + (threadIdx.x & 31);
    const int b = threadIdx.x >> 5;
    float acc = b1[u];
    const float* dp = dec + (size_t)b * D_DEC;
    for (int d = 0; d < D_DEC; ++d) acc += dp[d] * W1[(size_t)d * UNITS + u];
    query[(size_t)b * UNITS + u] = acc;
}

// ---------------- scores: M=65536 K=1024 N=512 f16 MFMA GEMM, fused tanh*V reduce.
// 2-way n-split: block = 128 rows x 256 cols, 8 waves of 64x64, BK=32, LDS dbuf,
// 2-phase pipeline.  __launch_bounds__(512,6): 3 blocks/CU (150 KB LDS) so the
// per-step vmcnt drain at the barrier overlaps two other blocks' compute.
#define BM 128
#define BN 256
#define BKK 32
#define NSTEP (D_DEC / BKK)

__global__ __launch_bounds__(512, 6) void k_scores(const float* __restrict__ enc,
                                                   const _Float16* __restrict__ W2h,
                                                   const float* __restrict__ query,
                                                   const float* __restrict__ b2,
                                                   const float* __restrict__ V,
                                                   float* __restrict__ psc) {
    __shared__ __align__(16) _Float16 Ab[2][BM * BKK];   // 2 x 8 KB
    __shared__ __align__(16) _Float16 Bb[2][BN * BKK];   // 2 x 16 KB
    __shared__ float sc_part[4][BM];                     // 2 KB

    const int tid  = threadIdx.x;
    const int lane = tid & 63;
    const int w    = tid >> 6;     // 0..7
    const int wr   = w >> 2;       // 0..1: rows [wr*64, +64)
    const int wc   = w & 3;        // 0..3: cols [wc*64, +64)
    const int g    = lane >> 4;    // 0..3
    const int r    = lane & 15;    // 0..15

    // XCD pairing: wg and wg+8 share %8 residue -> same XCD; map them to
    // the (n=0, n=1) pair of one m-tile.  mapped = (wg&7)*128 + (wg>>3), bijective.
    const unsigned wg = blockIdx.x;
    const int mapped = (int)((wg & 7) * 128 + (wg >> 3));
    const int m_blk  = mapped >> 1;
    const int n_blk  = mapped & 1;
    const int row0   = m_blk * BM;
    const int n0     = n_blk * BN;
    const int bat    = row0 >> 11;

    // A staging: thread -> row tid>>2, 8 fp32 at (tid&3)*8; swizzled LDS write
    const int arow = tid >> 2;
    const int acl  = tid & 3;
    const float* aptr = enc + (size_t)(row0 + arow) * D_ENC + acl * 8;
    const int a_wbyte = arow * 64 + ((acl * 16) ^ (((arow >> 1) & 3) << 4));

    f32x4 acc[4][4];
#pragma unroll
    for (int i = 0; i < 4; ++i)
#pragma unroll
        for (int j = 0; j < 4; ++j) acc[i][j] = (f32x4){0.f, 0.f, 0.f, 0.f};

    // ---- prologue: stage tile 0
    {
        const float4 p0 = *reinterpret_cast<const float4*>(aptr);
        const float4 p1 = *reinterpret_cast<const float4*>(aptr + 4);
#pragma unroll
        for (int i = 0; i < 2; ++i) {
            const int g16 = i * 512 + tid;           // 0..1023: 16B granules
            const int n   = g16 >> 2;                // 0..255
            const int j   = g16 & 3;
            const int kel = ((j * 16) ^ (((n >> 1) & 3) << 4)) >> 1;
            const _Float16* src = W2h + (size_t)(n0 + n) * D_DEC + kel;
            _Float16* dst = &Bb[0][g16 * 8];
            __builtin_amdgcn_global_load_lds(
                (const __attribute__((address_space(1))) void*)src,
                (__attribute__((address_space(3))) void*)dst, 16, 0, 0);
        }
        f16x8 h = {(_Float16)p0.x, (_Float16)p0.y, (_Float16)p0.z, (_Float16)p0.w,
                   (_Float16)p1.x, (_Float16)p1.y, (_Float16)p1.z, (_Float16)p1.w};
        *reinterpret_cast<f16x8*>((char*)&Ab[0][0] + a_wbyte) = h;
    }
    __syncthreads();

    // ---- main loop: one barrier per step
    for (int t = 0; t < NSTEP; ++t) {
        const int cur = t & 1;
        float4 p0, p1;
        if (t + 1 < NSTEP) {
            const int k0 = (t + 1) * BKK;
            p0 = *reinterpret_cast<const float4*>(aptr + k0);
            p1 = *reinterpret_cast<const float4*>(aptr + k0 + 4);
#pragma unroll
            for (int i = 0; i < 2; ++i) {
                const int g16 = i * 512 + tid;
                const int n   = g16 >> 2;
                const int j   = g16 & 3;
                const int kel = ((j * 16) ^ (((n >> 1) & 3) << 4)) >> 1;
                const _Float16* src = W2h + (size_t)(n0 + n) * D_DEC + k0 + kel;
                _Float16* dst = &Bb[cur ^ 1][g16 * 8];
                __builtin_amdgcn_global_load_lds(
                    (const __attribute__((address_space(1))) void*)src,
                    (__attribute__((address_space(3))) void*)dst, 16, 0, 0);
            }
        }

        f16x8 af[4], bf[4];
#pragma unroll
        for (int q = 0; q < 4; ++q) {
            const int rowa = wr * 64 + q * 16 + r;
            const int off  = rowa * 64 + ((g * 16) ^ (((rowa >> 1) & 3) << 4));
            af[q] = *reinterpret_cast<const f16x8*>((const char*)&Ab[cur][0] + off);
        }
#pragma unroll
        for (int q = 0; q < 4; ++q) {
            const int rowb = wc * 64 + q * 16 + r;
            const int off  = rowb * 64 + ((g * 16) ^ (((rowb >> 1) & 3) << 4));
            bf[q] = *reinterpret_cast<const f16x8*>((const char*)&Bb[cur][0] + off);
        }
#pragma unroll
        for (int fr = 0; fr < 4; ++fr)
#pragma unroll
            for (int fc = 0; fc < 4; ++fc)
                acc[fr][fc] = __builtin_amdgcn_mfma_f32_16x16x32_f16(
                    af[fr], bf[fc], acc[fr][fc], 0, 0, 0);

        if (t + 1 < NSTEP) {
            f16x8 h = {(_Float16)p0.x, (_Float16)p0.y, (_Float16)p0.z, (_Float16)p0.w,
                       (_Float16)p1.x, (_Float16)p1.y, (_Float16)p1.z, (_Float16)p1.w};
            *reinterpret_cast<f16x8*>((char*)&Ab[cur ^ 1][0] + a_wbyte) = h;
        }
        __syncthreads();
    }

    // ---- epilogue: partial over this block's 256 cols
    float qv[4], vv[4];
#pragma unroll
    for (int fc = 0; fc < 4; ++fc) {
        const int col = n0 + wc * 64 + fc * 16 + r;
        qv[fc] = query[(size_t)bat * UNITS + col] + b2[col];
        vv[fc] = V[col];
    }
    float ps[4][4];
#pragma unroll
    for (int fr = 0; fr < 4; ++fr)
#pragma unroll
        for (int i = 0; i < 4; ++i) ps[fr][i] = 0.f;
#pragma unroll
    for (int fc = 0; fc < 4; ++fc)
#pragma unroll
        for (int fr = 0; fr < 4; ++fr)
#pragma unroll
            for (int i = 0; i < 4; ++i)
                ps[fr][i] += tanh_fast(acc[fr][fc][i] + qv[fc]) * vv[fc];
#pragma unroll
    for (int off = 1; off < 16; off <<= 1)
#pragma unroll
        for (int fr = 0; fr < 4; ++fr)
#pragma unroll
            for (int i = 0; i < 4; ++i)
                ps[fr][i] += __shfl_xor(ps[fr][i], off, 64);
    if (r == 0)
#pragma unroll
        for (int fr = 0; fr < 4; ++fr)
#pragma unroll
            for (int i = 0; i < 4; ++i)
                sc_part[wc][wr * 64 + fr * 16 + g * 4 + i] = ps[fr][i];
    __syncthreads();
    if (tid < BM)
        psc[(size_t)n_blk * 65536 + row0 + tid] =
            sc_part[0][tid] + sc_part[1][tid] + sc_part[2][tid] + sc_part[3][tid];
}

// ---------------- softmax (merges 2 n-planes; bv dropped: shift-invariant)
__global__ __launch_bounds__(256) void k_softmax(const float* __restrict__ psc,
                                                 float* __restrict__ weights) {
    const int b = blockIdx.x;
    const int tid = threadIdx.x;
    __shared__ float wmax[4], wsum[4];
    float v[8];
    float lm = -1e30f;
#pragma unroll
    for (int i = 0; i < 8; ++i) {
        const size_t idx = (size_t)b * S_LEN + tid + i * 256;
        v[i] = psc[idx] + psc[65536 + idx];
        lm = fmaxf(lm, v[i]);
    }
    for (int off = 32; off; off >>= 1) lm = fmaxf(lm, __shfl_xor(lm, off, 64));
    if ((tid & 63) == 0) wmax[tid >> 6] = lm;
    __syncthreads();
    const float m = fmaxf(fmaxf(wmax[0], wmax[1]), fmaxf(wmax[2], wmax[3]));
    float ls = 0.f;
#pragma unroll
    for (int i = 0; i < 8; ++i) { v[i] = __expf(v[i] - m); ls += v[i]; }
    for (int off = 32; off; off >>= 1) ls += __shfl_xor(ls, off, 64);
    if ((tid & 63) == 0) wsum[tid >> 6] = ls;
    __syncthreads();
    const float inv = 1.f / (wsum[0] + wsum[1] + wsum[2] + wsum[3]);
#pragma unroll
    for (int i = 0; i < 8; ++i)
        weights[(size_t)b * S_LEN + tid + i * 256] = v[i] * inv;
}

// ---------------- context partials
#define SCH 128
#define NCH (S_LEN / SCH)
__global__ __launch_bounds__(256) void k_ctx_part(const float* __restrict__ enc,
                                                  const float* __restrict__ weights,
                                                  float* __restrict__ part) {
    const int b  = blockIdx.x >> 4;
    const int ch = blockIdx.x & 15;
    const int s0 = ch * SCH;
    const int d4 = threadIdx.x * 4;
    __shared__ float wl[SCH];
    if (threadIdx.x < SCH) wl[threadIdx.x] = weights[(size_t)b * S_LEN + s0 + threadIdx.x];
    __syncthreads();
    float4 a = {0.f, 0.f, 0.f, 0.f};
    const float* base = enc + (size_t)b * S_LEN * D_ENC + (size_t)s0 * D_ENC + d4;
#pragma unroll 4
    for (int s = 0; s < SCH; ++s) {
        const float4 e = *reinterpret_cast<const float4*>(base + (size_t)s * D_ENC);
        const float w = wl[s];
        a.x += w * e.x; a.y += w * e.y; a.z += w * e.z; a.w += w * e.w;
    }
    *reinterpret_cast<float4*>(&part[(size_t)blockIdx.x * D_ENC + d4]) = a;
}

__global__ __launch_bounds__(256) void k_ctx_combine(const float* __restrict__ part,
                                                     float* __restrict__ ctx) {
    const int idx = blockIdx.x * 256 + threadIdx.x;
    const int b = idx >> 10;
    const int d = idx & 1023;
    float s = 0.f;
#pragma unroll
    for (int c = 0; c < NCH; ++c) s += part[(size_t)(b * NCH + c) * D_ENC + d];
    ctx[idx] = s;
}

extern "C" void kernel_launch(void* const* d_in, const int* in_sizes, int n_in,
                              void* d_out, int out_size, void* d_ws, size_t ws_size,
                              hipStream_t stream) {
    const float* dec = (const float*)d_in[0];
    const float* enc = (const float*)d_in[1];
    const float* W1  = (const float*)d_in[2];
    const float* b1  = (const float*)d_in[3];
    const float* W2  = (const float*)d_in[4];
    const float* b2  = (const float*)d_in[5];
    const float* V   = (const float*)d_in[6];
    // bv unused: softmax shift-invariant

    float* out = (float*)d_out;
    float* out_ctx = out;
    float* out_w   = out + BATCH * D_ENC;

    char* ws = (char*)d_ws;
    _Float16* W2h = (_Float16*)(ws);                        // 1 MB
    float* query  = (float*)(ws + (1 << 20));               // 64 KB
    float* psc    = (float*)(ws + (1 << 20) + (1 << 16));   // 512 KB (2 planes)
    float* part   = (float*)(ws + (1 << 20) + (1 << 16) + (1 << 19)); // 2 MB

    k_prep_w2<<<dim3(D_DEC / 32, UNITS / 32), dim3(32, 8), 0, stream>>>(W2, W2h);
    k_query<<<UNITS / 32, 1024, 0, stream>>>(dec, W1, b1, query);
    k_scores<<<(BATCH * S_LEN) / BM * 2, 512, 0, stream>>>(enc, W2h, query, b2, V, psc);
    k_softmax<<<BATCH, 256, 0, stream>>>(psc, out_w);
    k_ctx_part<<<BATCH * NCH, 256, 0, stream>>>(enc, out_w, part);
    k_ctx_combine<<<(BATCH * D_ENC) / 256, 256, 0, stream>>>(part, out_ctx);
}

// Round 8
// 219.773 us; speedup vs baseline: 2.8902x; 2.8902x over previous
//
#include <hip/hip_runtime.h>
#include <hip/hip_bf16.h>
#include <hip/hip_fp16.h>

#define UNITS 512
#define D_DEC 1024
#define D_ENC 1024
#define BATCH 32
#define S_LEN 2048

typedef _Float16 f16x8 __attribute__((ext_vector_type(8)));
typedef float f32x4 __attribute__((ext_vector_type(4)));

__device__ inline float tanh_fast(float x) {
    float e = __expf(2.f * x);
    return 1.f - 2.f * __builtin_amdgcn_rcpf(e + 1.f);
}

// ---------------- prep: transpose + convert W2 [1024][512] f32 -> W2h [512][1024] f16
__global__ __launch_bounds__(256) void k_prep_w2(const float* __restrict__ W2,
                                                 _Float16* __restrict__ W2h) {
    __shared__ float tile[32][33];
    const int kb = blockIdx.x * 32;
    const int nb = blockIdx.y * 32;
    const int tx = threadIdx.x;
    const int ty = threadIdx.y;
    for (int i = 0; i < 32; i += 8)
        tile[ty + i][tx] = W2[(size_t)(kb + ty + i) * UNITS + nb + tx];
    __syncthreads();
    for (int i = 0; i < 32; i += 8)
        W2h[(size_t)(nb + ty + i) * D_DEC + kb + tx] = (_Float16)tile[tx][ty + i];
}

// ---------------- query
__global__ __launch_bounds__(1024) void k_query(const float* __restrict__ dec,
                                                const float* __restrict__ W1,
                                                const float* __restrict__ b1,
                                                float* __restrict__ query) {
    const int u = blockIdx.x * 32 + (threadIdx.x & 31);
    const int b = threadIdx.x >> 5;
    float acc = b1[u];
    const float* dp = dec + (size_t)b * D_DEC;
    for (int d = 0; d < D_DEC; ++d) acc += dp[d] * W1[(size_t)d * UNITS + u];
    query[(size_t)b * UNITS + u] = acc;
}

// ---------------- fused: scores GEMM (64 rows x full N=512) + chunk softmax stats
// + partial context from the block's own (cache-hot) enc tile.
// 8 waves of 64x64, BK=32, LDS dbuf, 2-phase pipeline (round-4 inner loop).
#define BM 64
#define BKK 32
#define NSTEP (D_DEC / BKK)

__global__ __launch_bounds__(512, 4) void k_fused(const float* __restrict__ enc,
                                                  const _Float16* __restrict__ W2h,
                                                  const float* __restrict__ query,
                                                  const float* __restrict__ b2,
                                                  const float* __restrict__ V,
                                                  float* __restrict__ scores,
                                                  float* __restrict__ chunk_m,
                                                  float* __restrict__ chunk_l,
                                                  float* __restrict__ part_ctx) {
    __shared__ __align__(16) _Float16 Ab[2][BM * BKK];      // 2 x 4 KB
    __shared__ __align__(16) _Float16 Bb[2][UNITS * BKK];   // 2 x 32 KB
    __shared__ float sc_part[8][BM];                        // 2 KB
    __shared__ float sc_e[BM];                              // 256 B

    const int tid  = threadIdx.x;
    const int lane = tid & 63;
    const int w    = tid >> 6;     // 0..7: cols [w*64, +64)
    const int g    = lane >> 4;    // 0..3
    const int r    = lane & 15;    // 0..15
    const int blk  = blockIdx.x;   // 0..1023
    const int row0 = blk * BM;
    const int bat  = row0 >> 11;

    // A staging: thread -> row tid>>3 (0..63), 4 fp32 at (tid&7)*4
    const int arow = tid >> 3;
    const int akc  = tid & 7;
    const float* aptr = enc + (size_t)(row0 + arow) * D_ENC + akc * 4;
    const int a_wbyte = arow * 64 + ((akc * 8) ^ (((arow >> 1) & 3) << 4));

    f32x4 acc[4][4];
#pragma unroll
    for (int i = 0; i < 4; ++i)
#pragma unroll
        for (int j = 0; j < 4; ++j) acc[i][j] = (f32x4){0.f, 0.f, 0.f, 0.f};

    // ---- prologue: stage tile 0
    {
        const float4 p0 = *reinterpret_cast<const float4*>(aptr);
#pragma unroll
        for (int i = 0; i < 4; ++i) {
            const int g16 = i * 512 + tid;           // 0..2047 16B granules
            const int n   = g16 >> 2;                // 0..511
            const int j   = g16 & 3;
            const int kel = ((j * 16) ^ (((n >> 1) & 3) << 4)) >> 1;
            const _Float16* src = W2h + (size_t)n * D_DEC + kel;
            __builtin_amdgcn_global_load_lds(
                (const __attribute__((address_space(1))) void*)src,
                (__attribute__((address_space(3))) void*)&Bb[0][g16 * 8], 16, 0, 0);
        }
        _Float16 h[4] = {(_Float16)p0.x, (_Float16)p0.y, (_Float16)p0.z, (_Float16)p0.w};
        *reinterpret_cast<float2*>((char*)&Ab[0][0] + a_wbyte) = *reinterpret_cast<float2*>(h);
    }
    __syncthreads();

    // ---- main loop: one barrier per step
    for (int t = 0; t < NSTEP; ++t) {
        const int cur = t & 1;
        float4 p0;
        if (t + 1 < NSTEP) {
            const int k0 = (t + 1) * BKK;
            p0 = *reinterpret_cast<const float4*>(aptr + k0);
#pragma unroll
            for (int i = 0; i < 4; ++i) {
                const int g16 = i * 512 + tid;
                const int n   = g16 >> 2;
                const int j   = g16 & 3;
                const int kel = ((j * 16) ^ (((n >> 1) & 3) << 4)) >> 1;
                const _Float16* src = W2h + (size_t)n * D_DEC + k0 + kel;
                __builtin_amdgcn_global_load_lds(
                    (const __attribute__((address_space(1))) void*)src,
                    (__attribute__((address_space(3))) void*)&Bb[cur ^ 1][g16 * 8], 16, 0, 0);
            }
        }

        f16x8 af[4], bf[4];
#pragma unroll
        for (int q = 0; q < 4; ++q) {
            const int rowa = q * 16 + r;
            const int off  = rowa * 64 + ((g * 16) ^ (((rowa >> 1) & 3) << 4));
            af[q] = *reinterpret_cast<const f16x8*>((const char*)&Ab[cur][0] + off);
        }
#pragma unroll
        for (int q = 0; q < 4; ++q) {
            const int rowb = w * 64 + q * 16 + r;
            const int off  = rowb * 64 + ((g * 16) ^ (((rowb >> 1) & 3) << 4));
            bf[q] = *reinterpret_cast<const f16x8*>((const char*)&Bb[cur][0] + off);
        }
#pragma unroll
        for (int fr = 0; fr < 4; ++fr)
#pragma unroll
            for (int fc = 0; fc < 4; ++fc)
                acc[fr][fc] = __builtin_amdgcn_mfma_f32_16x16x32_f16(
                    af[fr], bf[fc], acc[fr][fc], 0, 0, 0);

        if (t + 1 < NSTEP) {
            _Float16 h[4] = {(_Float16)p0.x, (_Float16)p0.y, (_Float16)p0.z, (_Float16)p0.w};
            *reinterpret_cast<float2*>((char*)&Ab[cur ^ 1][0] + a_wbyte) =
                *reinterpret_cast<float2*>(h);
        }
        __syncthreads();
    }

    // ---- epilogue 1: per-wave tanh*V partials over its 64-col group
    float qv[4], vv[4];
#pragma unroll
    for (int fc = 0; fc < 4; ++fc) {
        const int col = w * 64 + fc * 16 + r;
        qv[fc] = query[(size_t)bat * UNITS + col] + b2[col];
        vv[fc] = V[col];
    }
    float ps[4][4];
#pragma unroll
    for (int fr = 0; fr < 4; ++fr)
#pragma unroll
        for (int i = 0; i < 4; ++i) ps[fr][i] = 0.f;
#pragma unroll
    for (int fc = 0; fc < 4; ++fc)
#pragma unroll
        for (int fr = 0; fr < 4; ++fr)
#pragma unroll
            for (int i = 0; i < 4; ++i)
                ps[fr][i] += tanh_fast(acc[fr][fc][i] + qv[fc]) * vv[fc];
#pragma unroll
    for (int off = 1; off < 16; off <<= 1)
#pragma unroll
        for (int fr = 0; fr < 4; ++fr)
#pragma unroll
            for (int i = 0; i < 4; ++i)
                ps[fr][i] += __shfl_xor(ps[fr][i], off, 64);
    if (r == 0)
#pragma unroll
        for (int fr = 0; fr < 4; ++fr)
#pragma unroll
            for (int i = 0; i < 4; ++i)
                sc_part[w][fr * 16 + g * 4 + i] = ps[fr][i];
    __syncthreads();

    // ---- epilogue 2: chunk softmax stats (bv dropped: shift-invariant)
    if (tid < BM) {
        float s = 0.f;
#pragma unroll
        for (int ww = 0; ww < 8; ++ww) s += sc_part[ww][tid];
        scores[(size_t)row0 + tid] = s;
        float m = s;
#pragma unroll
        for (int off = 32; off; off >>= 1) m = fmaxf(m, __shfl_xor(m, off, 64));
        const float e = __expf(s - m);
        float l = e;
#pragma unroll
        for (int off = 32; off; off >>= 1) l += __shfl_xor(l, off, 64);
        sc_e[tid] = e;
        if (tid == 0) { chunk_m[blk] = m; chunk_l[blk] = l; }
    }
    __syncthreads();

    // ---- epilogue 3: partial context from this block's (cache-hot) enc tile
    {
        const int d0 = tid * 2;
        float cx = 0.f, cy = 0.f;
        const float* ebase = enc + (size_t)row0 * D_ENC + d0;
#pragma unroll 4
        for (int i = 0; i < BM; ++i) {
            const float wgt = sc_e[i];
            const float2 ev = *reinterpret_cast<const float2*>(ebase + (size_t)i * D_ENC);
            cx += wgt * ev.x; cy += wgt * ev.y;
        }
        float2 o = {cx, cy};
        *reinterpret_cast<float2*>(&part_ctx[(size_t)blk * D_ENC + d0]) = o;
    }
}

// ---------------- combine: per batch, merge 32 chunks (flash rescale) ->
// weights + context outputs.
__global__ __launch_bounds__(256) void k_combine(const float* __restrict__ scores,
                                                 const float* __restrict__ chunk_m,
                                                 const float* __restrict__ chunk_l,
                                                 const float* __restrict__ part_ctx,
                                                 float* __restrict__ out_ctx,
                                                 float* __restrict__ out_w) {
    const int b = blockIdx.x;
    const int tid = threadIdx.x;
    __shared__ float fc[32];
    __shared__ float Msh, Lsh;
    if (tid < 32) {
        const float m = chunk_m[b * 32 + tid];
        float M = m;
#pragma unroll
        for (int off = 16; off; off >>= 1) M = fmaxf(M, __shfl_xor(M, off, 64));
        const float f = __expf(m - M);
        float lf = chunk_l[b * 32 + tid] * f;
#pragma unroll
        for (int off = 16; off; off >>= 1) lf += __shfl_xor(lf, off, 64);
        fc[tid] = f;
        if (tid == 0) { Msh = M; Lsh = lf; }
    }
    __syncthreads();
    const float M = Msh;
    const float invL = 1.f / Lsh;
#pragma unroll
    for (int j = 0; j < 8; ++j) {
        const int s = tid + j * 256;
        out_w[(size_t)b * S_LEN + s] = __expf(scores[(size_t)b * S_LEN + s] - M) * invL;
    }
#pragma unroll
    for (int j = 0; j < 4; ++j) {
        const int d = tid + j * 256;
        float sacc = 0.f;
        for (int c = 0; c < 32; ++c)
            sacc += part_ctx[(size_t)(b * 32 + c) * D_ENC + d] * fc[c];
        out_ctx[(size_t)b * D_ENC + d] = sacc * invL;
    }
}

extern "C" void kernel_launch(void* const* d_in, const int* in_sizes, int n_in,
                              void* d_out, int out_size, void* d_ws, size_t ws_size,
                              hipStream_t stream) {
    const float* dec = (const float*)d_in[0];
    const float* enc = (const float*)d_in[1];
    const float* W1  = (const float*)d_in[2];
    const float* b1  = (const float*)d_in[3];
    const float* W2  = (const float*)d_in[4];
    const float* b2  = (const float*)d_in[5];
    const float* V   = (const float*)d_in[6];
    // bv unused: softmax shift-invariant

    float* out = (float*)d_out;
    float* out_ctx = out;                 // [32,1024]
    float* out_w   = out + BATCH * D_ENC; // [32,2048]

    char* ws = (char*)d_ws;
    _Float16* W2h  = (_Float16*)(ws);                          // 1 MB
    float* query   = (float*)(ws + (1 << 20));                 // 64 KB
    float* scores  = (float*)(ws + (1 << 20) + (1 << 16));     // 256 KB
    float* chunk_m = (float*)(ws + (1 << 20) + (1 << 16) + (1 << 18));          // 4 KB
    float* chunk_l = (float*)(ws + (1 << 20) + (1 << 16) + (1 << 18) + 4096);   // 4 KB
    float* part_ctx = (float*)(ws + (1 << 20) + (1 << 16) + (1 << 18) + 8192);  // 4 MB

    k_prep_w2<<<dim3(D_DEC / 32, UNITS / 32), dim3(32, 8), 0, stream>>>(W2, W2h);
    k_query<<<UNITS / 32, 1024, 0, stream>>>(dec, W1, b1, query);
    k_fused<<<(BATCH * S_LEN) / BM, 512, 0, stream>>>(enc, W2h, query, b2, V,
                                                      scores, chunk_m, chunk_l, part_ctx);
    k_combine<<<BATCH, 256, 0, stream>>>(scores, chunk_m, chunk_l, part_ctx,
                                         out_ctx, out_w);
}